// Round 7
// baseline (2437.429 us; speedup 1.0000x reference)
//
#include <hip/hip_runtime.h>

#define TT 2048

typedef _Float16 f16;
typedef _Float16 f16x2 __attribute__((ext_vector_type(2)));
typedef unsigned int u32;

static __device__ __forceinline__ float fdot2f(u32 a, u32 b, float c) {
  return __builtin_amdgcn_fdot2(__builtin_bit_cast(f16x2, a),
                                __builtin_bit_cast(f16x2, b), c, false);
}
static __device__ __forceinline__ u32 packh2(float a, float b) {
  f16x2 v; v[0] = (f16)a; v[1] = (f16)b;
  return __builtin_bit_cast(u32, v);
}
static __device__ __forceinline__ float sigm(float x) {
  return 1.f / (1.f + __expf(-x));
}
static __device__ __forceinline__ float tanh_(float x) {
  x = fminf(15.f, fmaxf(-15.f, x));
  const float e = __expf(2.f * x);
  return (e - 1.f) / (e + 1.f);
}

// pack 4 f32-pairs (8 floats) into one uint4 of f16x2
#define PK4(P2, O) make_uint4( \
  packh2((P2)[(O)    ].x, (P2)[(O)    ].y), \
  packh2((P2)[(O) + 1].x, (P2)[(O) + 1].y), \
  packh2((P2)[(O) + 2].x, (P2)[(O) + 2].y), \
  packh2((P2)[(O) + 3].x, (P2)[(O) + 3].y))

#define LOADROW8(PTR, W0,W1,W2,W3,W4,W5,W6,W7) do { \
  const float2* _p2 = (const float2*)(PTR); \
  W0 = PK4(_p2, 0);  W1 = PK4(_p2, 4);  W2 = PK4(_p2, 8);  W3 = PK4(_p2, 12); \
  W4 = PK4(_p2, 16); W5 = PK4(_p2, 20); W6 = PK4(_p2, 24); W7 = PK4(_p2, 28); } while (0)

#define LOADROW4(PTR, W0,W1,W2,W3) do { \
  const float2* _p2 = (const float2*)(PTR); \
  W0 = PK4(_p2, 0);  W1 = PK4(_p2, 4);  W2 = PK4(_p2, 8);  W3 = PK4(_p2, 12); } while (0)

// 4 fdot2 of one weight-uint4 against one operand-uint4
#define FDG(W, V, ACC) do { \
  ACC = fdot2f((W).x, (V).x, ACC); \
  ACC = fdot2f((W).y, (V).y, ACC); \
  ACC = fdot2f((W).z, (V).z, ACC); \
  ACC = fdot2f((W).w, (V).w, ACC); } while (0)

#define LAUND(W) asm volatile("" : "+v"((W).x), "+v"((W).y), "+v"((W).z), "+v"((W).w))

// full 64-wide dot for 4 gates (operand = 32 u32 in LDS)
#define GATES4(XP, A0, A1, A2, A3) do { \
  uint4 _v; \
  _v = *(const uint4*)&(XP)[0];  FDG(wA0,_v,A0); FDG(wB0,_v,A1); FDG(wC0,_v,A2); FDG(wD0,_v,A3); \
  _v = *(const uint4*)&(XP)[4];  FDG(wA1,_v,A0); FDG(wB1,_v,A1); FDG(wC1,_v,A2); FDG(wD1,_v,A3); \
  _v = *(const uint4*)&(XP)[8];  FDG(wA2,_v,A0); FDG(wB2,_v,A1); FDG(wC2,_v,A2); FDG(wD2,_v,A3); \
  _v = *(const uint4*)&(XP)[12]; FDG(wA3,_v,A0); FDG(wB3,_v,A1); FDG(wC3,_v,A2); FDG(wD3,_v,A3); \
  _v = *(const uint4*)&(XP)[16]; FDG(wA4,_v,A0); FDG(wB4,_v,A1); FDG(wC4,_v,A2); FDG(wD4,_v,A3); \
  _v = *(const uint4*)&(XP)[20]; FDG(wA5,_v,A0); FDG(wB5,_v,A1); FDG(wC5,_v,A2); FDG(wD5,_v,A3); \
  _v = *(const uint4*)&(XP)[24]; FDG(wA6,_v,A0); FDG(wB6,_v,A1); FDG(wC6,_v,A2); FDG(wD6,_v,A3); \
  _v = *(const uint4*)&(XP)[28]; FDG(wA7,_v,A0); FDG(wB7,_v,A1); FDG(wC7,_v,A2); FDG(wD7,_v,A3); \
} while (0)

// layer-2: 64-wide dot for 2 gates over h1 (wA,wB)
#define GATES2IH(XP, B0, B1) do { \
  uint4 _v; \
  _v = *(const uint4*)&(XP)[0];  FDG(wA0,_v,B0); FDG(wB0,_v,B1); \
  _v = *(const uint4*)&(XP)[4];  FDG(wA1,_v,B0); FDG(wB1,_v,B1); \
  _v = *(const uint4*)&(XP)[8];  FDG(wA2,_v,B0); FDG(wB2,_v,B1); \
  _v = *(const uint4*)&(XP)[12]; FDG(wA3,_v,B0); FDG(wB3,_v,B1); \
  _v = *(const uint4*)&(XP)[16]; FDG(wA4,_v,B0); FDG(wB4,_v,B1); \
  _v = *(const uint4*)&(XP)[20]; FDG(wA5,_v,B0); FDG(wB5,_v,B1); \
  _v = *(const uint4*)&(XP)[24]; FDG(wA6,_v,B0); FDG(wB6,_v,B1); \
  _v = *(const uint4*)&(XP)[28]; FDG(wA7,_v,B0); FDG(wB7,_v,B1); \
} while (0)

// layer-2: 32-wide dot for 2 gates over h2 (wC0..3, wD0..3)
#define GATES2HH(XP, B0, B1) do { \
  uint4 _v; \
  _v = *(const uint4*)&(XP)[0];  FDG(wC0,_v,B0); FDG(wD0,_v,B1); \
  _v = *(const uint4*)&(XP)[4];  FDG(wC1,_v,B0); FDG(wD1,_v,B1); \
  _v = *(const uint4*)&(XP)[8];  FDG(wC2,_v,B0); FDG(wD2,_v,B1); \
  _v = *(const uint4*)&(XP)[12]; FDG(wC3,_v,B0); FDG(wD3,_v,B1); \
} while (0)

// 3 specialized waves per row (structure == R4). Weights are 32 NAMED uint4
// per wave (no array!): R3-R6 showed the w[4][32] array was SROA-demoted to
// scratch and re-loaded (or remat'd: reload+repack) every one of 2048
// iterations -- the entire 2000-2500us plateau. Named uint4 values with only
// compile-time member accesses cannot be demoted; the asm launder pins them
// as non-rematerializable. ~160-200 live regs under cap 512 (192,1).
__launch_bounds__(192, 1)
__global__ void lstm2_pc5_kernel(const float* __restrict__ x1,
                                 const float* __restrict__ x2,
                                 const float* __restrict__ Wih1,
                                 const float* __restrict__ Whh1,
                                 const float* __restrict__ bih1,
                                 const float* __restrict__ bhh1,
                                 const float* __restrict__ Wih2,
                                 const float* __restrict__ Whh2,
                                 const float* __restrict__ bih2,
                                 const float* __restrict__ bhh2,
                                 float* __restrict__ out)
{
  __shared__ __align__(16) u32 s_xbig[8][32];    // x ring, f16 pairs
  __shared__ __align__(16) u32 s_h1[2][32];      // h1 double buffer
  __shared__ __align__(16) u32 s_h2[16];         // h2 (wave2-private)
  __shared__ __align__(16) float s_pre[4][256];  // pre1 ring, f32

  const int tid = threadIdx.x;
  const int lane = tid & 63;
  const int wid = tid >> 6;
  const int bid = blockIdx.x;
  const int which = bid >> 8;      // 0 -> x1, 1 -> x2
  const int row = bid & 255;
  const float* __restrict__ xg = (which ? x2 : x1) + row * (TT * 64) + lane;

  const uint4 z4 = make_uint4(0u, 0u, 0u, 0u);
  uint4 wA0=z4,wA1=z4,wA2=z4,wA3=z4,wA4=z4,wA5=z4,wA6=z4,wA7=z4;
  uint4 wB0=z4,wB1=z4,wB2=z4,wB3=z4,wB4=z4,wB5=z4,wB6=z4,wB7=z4;
  uint4 wC0=z4,wC1=z4,wC2=z4,wC3=z4,wC4=z4,wC5=z4,wC6=z4,wC7=z4;
  uint4 wD0=z4,wD1=z4,wD2=z4,wD3=z4,wD4=z4,wD5=z4,wD6=z4,wD7=z4;
  float bias0 = 0.f, bias1 = 0.f, bias2 = 0.f, bias3 = 0.f;

  if (wid == 0) {
    LOADROW8(Wih1 + (lane      ) * 64, wA0,wA1,wA2,wA3,wA4,wA5,wA6,wA7);
    LOADROW8(Wih1 + (lane +  64) * 64, wB0,wB1,wB2,wB3,wB4,wB5,wB6,wB7);
    LOADROW8(Wih1 + (lane + 128) * 64, wC0,wC1,wC2,wC3,wC4,wC5,wC6,wC7);
    LOADROW8(Wih1 + (lane + 192) * 64, wD0,wD1,wD2,wD3,wD4,wD5,wD6,wD7);
    bias0 = bih1[lane] + bhh1[lane];
    bias1 = bih1[lane + 64] + bhh1[lane + 64];
    bias2 = bih1[lane + 128] + bhh1[lane + 128];
    bias3 = bih1[lane + 192] + bhh1[lane + 192];
  } else if (wid == 1) {
    LOADROW8(Whh1 + (lane      ) * 64, wA0,wA1,wA2,wA3,wA4,wA5,wA6,wA7);
    LOADROW8(Whh1 + (lane +  64) * 64, wB0,wB1,wB2,wB3,wB4,wB5,wB6,wB7);
    LOADROW8(Whh1 + (lane + 128) * 64, wC0,wC1,wC2,wC3,wC4,wC5,wC6,wC7);
    LOADROW8(Whh1 + (lane + 192) * 64, wD0,wD1,wD2,wD3,wD4,wD5,wD6,wD7);
    if (lane < 32) s_h1[1][lane] = 0u;   // h1[-1] in slot (-1)&1 == 1
  } else {
    LOADROW8(Wih2 + (lane     ) * 64, wA0,wA1,wA2,wA3,wA4,wA5,wA6,wA7);
    LOADROW8(Wih2 + (lane + 64) * 64, wB0,wB1,wB2,wB3,wB4,wB5,wB6,wB7);
    LOADROW4(Whh2 + (lane     ) * 32, wC0,wC1,wC2,wC3);
    LOADROW4(Whh2 + (lane + 64) * 32, wD0,wD1,wD2,wD3);
    bias0 = bih2[lane] + bhh2[lane];
    bias1 = bih2[lane + 64] + bhh2[lane + 64];
    if (lane < 16) s_h2[lane] = 0u;
  }

  // pin every weight value (non-rematerializable, stays in a VGPR)
  LAUND(wA0); LAUND(wA1); LAUND(wA2); LAUND(wA3);
  LAUND(wA4); LAUND(wA5); LAUND(wA6); LAUND(wA7);
  LAUND(wB0); LAUND(wB1); LAUND(wB2); LAUND(wB3);
  LAUND(wB4); LAUND(wB5); LAUND(wB6); LAUND(wB7);
  LAUND(wC0); LAUND(wC1); LAUND(wC2); LAUND(wC3);
  LAUND(wC4); LAUND(wC5); LAUND(wC6); LAUND(wC7);
  LAUND(wD0); LAUND(wD1); LAUND(wD2); LAUND(wD3);
  LAUND(wD4); LAUND(wD5); LAUND(wD6); LAUND(wD7);
  asm volatile("" : "+v"(bias0), "+v"(bias1), "+v"(bias2), "+v"(bias3));

  float c1 = 0.f, c2 = 0.f;
  float xr0 = 0.f, xr1 = 0.f, xr2 = 0.f, xr3 = 0.f;
  float xr4 = 0.f, xr5 = 0.f, xr6 = 0.f, xr7 = 0.f;

  // ---- prologue (waveP): x[0],x[1] -> slots 0,1; pre[0],pre[1]; prime xr ----
  if (wid == 0) {
    ((f16*)s_xbig[0])[lane] = (f16)xg[0];
    ((f16*)s_xbig[1])[lane] = (f16)xg[64];
    #pragma unroll
    for (int p = 0; p < 2; ++p) {
      float a0 = bias0, a1 = bias1, a2 = bias2, a3 = bias3;
      const u32* xp = s_xbig[p];
      GATES4(xp, a0, a1, a2, a3);
      s_pre[p][lane]       = a0;
      s_pre[p][lane + 64]  = a1;
      s_pre[p][lane + 128] = a2;
      s_pre[p][lane + 192] = a3;
    }
    xr0 = xg[2 * 64]; xr1 = xg[3 * 64]; xr2 = xg[4 * 64]; xr3 = xg[5 * 64];
    xr4 = xg[6 * 64]; xr5 = xg[7 * 64]; xr6 = xg[8 * 64]; xr7 = xg[9 * 64];
  }
  __syncthreads();

  #pragma unroll 1
  for (int i = 0; i <= TT; ++i) {
    if (wid == 0) {
      if ((i & 7) == 0) {
        // commit xr (= x[i+2 .. i+9]) to ring slots (t & 7)
        ((f16*)s_xbig[(i + 2) & 7])[lane] = (f16)xr0;
        ((f16*)s_xbig[(i + 3) & 7])[lane] = (f16)xr1;
        ((f16*)s_xbig[(i + 4) & 7])[lane] = (f16)xr2;
        ((f16*)s_xbig[(i + 5) & 7])[lane] = (f16)xr3;
        ((f16*)s_xbig[(i + 6) & 7])[lane] = (f16)xr4;
        ((f16*)s_xbig[(i + 7) & 7])[lane] = (f16)xr5;
        ((f16*)s_xbig[(i + 8) & 7])[lane] = (f16)xr6;
        ((f16*)s_xbig[(i + 9) & 7])[lane] = (f16)xr7;
        // issue next batch x[i+10 .. i+17] (clamped; clamped values unused)
        const int tm = TT - 1;
        xr0 = xg[(i + 10 < TT ? i + 10 : tm) * 64];
        xr1 = xg[(i + 11 < TT ? i + 11 : tm) * 64];
        xr2 = xg[(i + 12 < TT ? i + 12 : tm) * 64];
        xr3 = xg[(i + 13 < TT ? i + 13 : tm) * 64];
        xr4 = xg[(i + 14 < TT ? i + 14 : tm) * 64];
        xr5 = xg[(i + 15 < TT ? i + 15 : tm) * 64];
        xr6 = xg[(i + 16 < TT ? i + 16 : tm) * 64];
        xr7 = xg[(i + 17 < TT ? i + 17 : tm) * 64];
      }
      if (i + 2 < TT) {
        float a0 = bias0, a1 = bias1, a2 = bias2, a3 = bias3;
        const u32* xp = s_xbig[(i + 2) & 7];
        GATES4(xp, a0, a1, a2, a3);
        const int sl = (i + 2) & 3;
        s_pre[sl][lane]       = a0;
        s_pre[sl][lane + 64]  = a1;
        s_pre[sl][lane + 128] = a2;
        s_pre[sl][lane + 192] = a3;
      }
    } else if (wid == 1) {
      // layer-1 step i: h1_i = LSTM1(pre[i], h1_{i-1}); lane-local update
      if (i < TT) {
        const float* pr = s_pre[i & 3];
        float a0 = pr[lane], a1 = pr[lane + 64];
        float a2 = pr[lane + 128], a3 = pr[lane + 192];
        const u32* hp = s_h1[(i + 1) & 1];          // h1[i-1]
        GATES4(hp, a0, a1, a2, a3);
        const float i1 = sigm(a0), f1 = sigm(a1), g1 = tanh_(a2), o1 = sigm(a3);
        c1 = f1 * c1 + i1 * g1;
        const float h1v = o1 * tanh_(c1);
        ((f16*)s_h1[i & 1])[lane] = (f16)h1v;
      }
    } else {
      // layer-2, one step behind: t = i-1
      if (i > 0) {
        const int t = i - 1;
        float b0 = bias0, b1_ = bias1;
        const u32* hp = s_h1[t & 1];                // h1[t]
        GATES2IH(hp, b0, b1_);
        GATES2HH(s_h2, b0, b1_);                    // h2[t-1]
        const float p0 = __shfl_xor(b0, 32, 64);
        const float p1 = __shfl_xor(b1_, 32, 64);
        const bool lo = lane < 32;
        const float gi = lo ? b0  : p0;
        const float gf = lo ? p0  : b0;
        const float gg = lo ? b1_ : p1;
        const float go = lo ? p1  : b1_;
        const float i2 = sigm(gi), f2 = sigm(gf), g2v = tanh_(gg), o2 = sigm(go);
        c2 = f2 * c2 + i2 * g2v;
        const float h2v = o2 * tanh_(c2);
        if (lo) ((f16*)s_h2)[lane] = (f16)h2v;
        if (t == TT - 1 && lo) out[which * 8192 + row * 32 + lane] = h2v;
      }
    }
    __syncthreads();
  }
}

extern "C" void kernel_launch(void* const* d_in, const int* in_sizes, int n_in,
                              void* d_out, int out_size, void* d_ws, size_t ws_size,
                              hipStream_t stream) {
  const float* x1   = (const float*)d_in[0];
  const float* x2   = (const float*)d_in[1];
  const float* Wih1 = (const float*)d_in[2];
  const float* Whh1 = (const float*)d_in[3];
  const float* bih1 = (const float*)d_in[4];
  const float* bhh1 = (const float*)d_in[5];
  const float* Wih2 = (const float*)d_in[6];
  const float* Whh2 = (const float*)d_in[7];
  const float* bih2 = (const float*)d_in[8];
  const float* bhh2 = (const float*)d_in[9];
  float* out = (float*)d_out;

  lstm2_pc5_kernel<<<dim3(512), dim3(192), 0, stream>>>(
      x1, x2, Wih1, Whh1, bih1, bhh1, Wih2, Whh2, bih2, bhh2, out);
}